// Round 7
// baseline (216.289 us; speedup 1.0000x reference)
//
#include <hip/hip_runtime.h>
#include <hip/hip_bf16.h>
#include <stdint.h>

#define S_LEN 2048
#define DIMSZ 2048
#define NH    16
#define HD    128
#define NQK   2176   // Q cols (2048) + K cols (128); V cols start here
#define NQKV  2304
#define NT2   (S_LEN / 128)

typedef short  bf16x8  __attribute__((ext_vector_type(8)));
typedef float  floatx4 __attribute__((ext_vector_type(4)));
typedef float  floatx16 __attribute__((ext_vector_type(16)));
typedef int    intx4   __attribute__((ext_vector_type(4)));
typedef unsigned short u16;

#define mfma32 __builtin_amdgcn_mfma_f32_32x32x16_bf16
#define LOG2E 1.4426950408889634f

// round-to-nearest-even f32 -> bf16 bits
__device__ __forceinline__ u16 f2bf(float x) {
  unsigned int u = __builtin_bit_cast(unsigned int, x);
  u = (u + 0x7FFFu + ((u >> 16) & 1u)) >> 16;
  return (u16)u;
}

// v_cvt_pk_bf16_f32: word = (bf16(hi)<<16) | bf16(lo)   (plain VALU, no hazard)
__device__ __forceinline__ int cvtpk(float lo, float hi) {
  int r;
  asm("v_cvt_pk_bf16_f32 %0, %1, %2" : "=v"(r) : "v"(lo), "v"(hi));
  return r;
}

// 2^x — builtin so the compiler handles the TRANS wait-state hazard
#if __has_builtin(__builtin_amdgcn_exp2f)
__device__ __forceinline__ float fexp2(float x) { return __builtin_amdgcn_exp2f(x); }
#else
__device__ __forceinline__ float fexp2(float x) { return exp2f(x); }
#endif

// half swap via BUILTIN (hazard-modeled): a'[32:63]=b[0:31], b'[0:31]=a[32:63]
#if __has_builtin(__builtin_amdgcn_permlane32_swap)
__device__ __forceinline__ void half_swap(int& a, int& b) {
  auto r = __builtin_amdgcn_permlane32_swap(a, b, false, false);
  a = (int)r[0]; b = (int)r[1];
}
__device__ __forceinline__ float red_max32(float x) {
  int xi = __builtin_bit_cast(int, x);
  auto r = __builtin_amdgcn_permlane32_swap(xi, xi, false, false);
  return fmaxf(__builtin_bit_cast(float, (int)r[0]), __builtin_bit_cast(float, (int)r[1]));
}
__device__ __forceinline__ float red_add32(float x) {
  int xi = __builtin_bit_cast(int, x);
  auto r = __builtin_amdgcn_permlane32_swap(xi, xi, false, false);
  return __builtin_bit_cast(float, (int)r[0]) + __builtin_bit_cast(float, (int)r[1]);
}
#else
__device__ __forceinline__ void half_swap(int& a, int& b) {
  int as = __shfl_xor(a, 32);
  int bs = __shfl_xor(b, 32);
  int lane = threadIdx.x & 63;
  int na = (lane < 32) ? a : bs;
  int nb = (lane < 32) ? as : b;
  a = na; b = nb;
}
__device__ __forceinline__ float red_max32(float x) { return fmaxf(x, __shfl_xor(x, 32)); }
__device__ __forceinline__ float red_add32(float x) { return x + __shfl_xor(x, 32); }
#endif

// async global->LDS, 16 bytes per lane; LDS dest wave-uniform base (+lane*16 by HW)
__device__ __forceinline__ void gload16(const void* g, void* l) {
  __builtin_amdgcn_global_load_lds(
      reinterpret_cast<const __attribute__((address_space(1))) void*>(reinterpret_cast<uintptr_t>(g)),
      reinterpret_cast<__attribute__((address_space(3))) void*>(reinterpret_cast<uintptr_t>(l)),
      16, 0, 0);
}

// ---------------- converts ----------------
__global__ void k_cvt_bf16(const float* __restrict__ in, u16* __restrict__ out, int n4) {
  int i = blockIdx.x * blockDim.x + threadIdx.x;
  if (i < n4) {
    float4 v = ((const float4*)in)[i];
    ushort4 o;
    o.x = f2bf(v.x); o.y = f2bf(v.y); o.z = f2bf(v.z); o.w = f2bf(v.w);
    ((ushort4*)out)[i] = o;
  }
}

// in: (K x N) f32 row-major  ->  out rows [rowOff .. rowOff+N): (N x K) bf16
__global__ void k_transpose_bf16(const float* __restrict__ in, u16* __restrict__ out,
                                 int K, int N, int rowOff) {
  __shared__ float t[64][65];
  int c0 = blockIdx.x * 64;   // N dim
  int r0 = blockIdx.y * 64;   // K dim
  int tid = threadIdx.x;
  int lr = tid >> 6;          // 0..3
  int lc = tid & 63;
#pragma unroll
  for (int i = 0; i < 16; ++i) {
    int r = lr + i * 4;
    t[r][lc] = in[(size_t)(r0 + r) * N + c0 + lc];
  }
  __syncthreads();
#pragma unroll
  for (int i = 0; i < 16; ++i) {
    int r = lr + i * 4;  // row of transposed tile (= col of in)
    out[(size_t)(rowOff + c0 + r) * K + r0 + lc] = f2bf(t[lc][r]);
  }
}

__global__ void k_bias_concat(const float* __restrict__ bq, const float* __restrict__ bk,
                              const float* __restrict__ bv, float* __restrict__ out) {
  int i = blockIdx.x * 256 + threadIdx.x;
  if (i < NQKV) out[i] = (i < 2048) ? bq[i] : (i < NQK ? bk[i - 2048] : bv[i - NQK]);
}

// ---------------- GEMM: C(MxN) = A(MxK) * Bt(NxK)^T + bias  (R4-proven 128² version) ----
__device__ __forceinline__ void stage_tile(const u16* __restrict__ G, int ldg, int row0, int kt,
                                           u16* lbase, int wid, int lane) {
#pragma unroll
  for (int i = 0; i < 4; ++i) {
    int c   = (wid * 4 + i) * 64 + lane;
    int row = c >> 3, cin = c & 7;
    int cs  = cin ^ (row & 7);  // source pre-swizzle (rule #21)
    const u16* g = G + (size_t)(row0 + row) * ldg + kt * 64 + cs * 8;
    gload16(g, (char*)lbase + (wid * 4 + i) * 1024);
  }
}

template <int OMODE>
__global__ __launch_bounds__(256)
void k_gemm(const u16* __restrict__ A, const u16* __restrict__ Bt,
            const float* __restrict__ bias, void* __restrict__ Cout,
            u16* __restrict__ vt, int M, int N, int K) {
  __shared__ u16 lA[2][128 * 64];
  __shared__ u16 lB[2][128 * 64];
  const int tid = threadIdx.x, lane = tid & 63, wid = tid >> 6;
  const int wm = wid >> 1, wn = wid & 1;
  const int tm = blockIdx.x, tn = blockIdx.y;
  const int nk = K >> 6;

  stage_tile(A, K, tm * 128, 0, lA[0], wid, lane);
  stage_tile(Bt, K, tn * 128, 0, lB[0], wid, lane);
  __syncthreads();

  floatx4 acc[4][4] = {};
  int buf = 0;
  for (int kt = 0; kt < nk; ++kt) {
    if (kt + 1 < nk) {
      stage_tile(A, K, tm * 128, kt + 1, lA[buf ^ 1], wid, lane);
      stage_tile(Bt, K, tn * 128, kt + 1, lB[buf ^ 1], wid, lane);
    }
    const char* pa = (const char*)&lA[buf][0];
    const char* pb = (const char*)&lB[buf][0];
#pragma unroll
    for (int kk = 0; kk < 2; ++kk) {
      bf16x8 af[4], bfr[4];
      int gch = kk * 4 + (lane >> 4);
#pragma unroll
      for (int f = 0; f < 4; ++f) {
        int ra = wm * 64 + f * 16 + (lane & 15);
        af[f]  = *(const bf16x8*)(pa + ra * 128 + ((gch ^ (ra & 7)) << 4));
        int rb = wn * 64 + f * 16 + (lane & 15);
        bfr[f] = *(const bf16x8*)(pb + rb * 128 + ((gch ^ (rb & 7)) << 4));
      }
      __builtin_amdgcn_s_setprio(1);
#pragma unroll
      for (int fm = 0; fm < 4; ++fm)
#pragma unroll
        for (int fn = 0; fn < 4; ++fn)
          acc[fm][fn] = __builtin_amdgcn_mfma_f32_16x16x32_bf16(af[fm], bfr[fn], acc[fm][fn], 0, 0, 0);
      __builtin_amdgcn_s_setprio(0);
    }
    __syncthreads();
    buf ^= 1;
  }

#pragma unroll
  for (int fm = 0; fm < 4; ++fm)
#pragma unroll
    for (int fn = 0; fn < 4; ++fn)
#pragma unroll
      for (int r = 0; r < 4; ++r) {
        int rowg = tm * 128 + wm * 64 + fm * 16 + (lane >> 4) * 4 + r;
        int colg = tn * 128 + wn * 64 + fn * 16 + (lane & 15);
        float v = acc[fm][fn][r] + bias[colg];
        if constexpr (OMODE == 1) {
          ((float*)Cout)[(size_t)rowg * N + colg] = v;
        } else {
          if (colg < NQK) {
            ((u16*)Cout)[(size_t)rowg * N + colg] = f2bf(v);
          } else {  // V: store transposed vt[b][d][s]
            int d = colg - NQK;
            int bg = rowg >> 11, s = rowg & 2047;
            vt[((size_t)bg * HD + d) * S_LEN + s] = f2bf(v);
          }
        }
      }
}

// ---------------- flash attention (8-wave, swapped-operand, KVBLK=128) ----------
// grid (S/32, 2, B); 512 threads = 8 waves; wave w = head hg*8+w, all on same 32 q-rows.
// K tile: 128 k-rows x 128 d (256B rows); V^T tile: 128 d-rows x 128 k (256B rows).
// Swizzle: slot = chunk ^ (row & 15)  (2-way max bank aliasing on reads).
__device__ __forceinline__ void stage_k128(const u16* __restrict__ qkv, int b, int kt,
                                           u16* lK, int wid, int lane) {
#pragma unroll
  for (int i = 0; i < 4; ++i) {
    int seg = wid * 4 + i;             // 0..31, 1KB each
    int r = seg * 4 + (lane >> 4);     // k-row 0..127
    int cin = lane & 15;
    int cs = cin ^ (r & 15);           // source pre-swizzle (rule #21)
    const u16* g = qkv + (size_t)(b * S_LEN + kt * 128 + r) * NQKV + 2048 + cs * 8;
    gload16(g, (char*)lK + seg * 1024);
  }
}
__device__ __forceinline__ void stage_v128(const u16* __restrict__ vt, int b, int kt,
                                           u16* lV, int wid, int lane) {
#pragma unroll
  for (int i = 0; i < 4; ++i) {
    int seg = wid * 4 + i;
    int r = seg * 4 + (lane >> 4);     // d-row 0..127
    int cin = lane & 15;
    int cs = cin ^ (r & 15);
    const u16* g = vt + ((size_t)b * HD + r) * S_LEN + kt * 128 + cs * 8;
    gload16(g, (char*)lV + seg * 1024);
  }
}

__global__ __launch_bounds__(512, 2)
void k_attn(const u16* __restrict__ qkv, const u16* __restrict__ vt,
            const float* __restrict__ mask, u16* __restrict__ attn) {
  __shared__ __align__(16) u16 lK[2][128 * 128];   // 32KB x2
  __shared__ __align__(16) u16 lV[2][128 * 128];   // 32KB x2
  const int tid = threadIdx.x, lane = tid & 63, wid = tid >> 6;
  const int qt = blockIdx.x, hg = blockIdx.y, b = blockIdx.z;
  const int h = hg * 8 + wid;
  const int q = lane & 31, h5 = lane >> 5;
  const float scale = 0.08838834764831845f;  // 1/sqrt(128)

  // hoist Q (B-frag: col=q, d = cs*16 + h5*8 + idx)
  bf16x8 qf[8];
  const size_t qrow = (size_t)(b * S_LEN + qt * 32 + q);
#pragma unroll
  for (int cs = 0; cs < 8; ++cs)
    qf[cs] = *(const bf16x8*)(qkv + qrow * NQKV + h * HD + cs * 16 + h5 * 8);

  // hoisted LDS byte offsets (loop-invariant)
  int offK[8], offV[8];
#pragma unroll
  for (int cs = 0; cs < 8; ++cs)
    offK[cs] = q * 256 + (((cs * 2 + h5) ^ (q & 15)) << 4);
#pragma unroll
  for (int hf = 0; hf < 2; ++hf)
#pragma unroll
    for (int ks = 0; ks < 4; ++ks)
      offV[hf * 4 + ks] = q * 256 + (((hf * 8 + ks * 2 + h5) ^ (q & 15)) << 4);

  // per-lane mask pointer: row = qrow, col base = h5*4 (ln-domain, raw)
  const float* mptr = mask + ((size_t)b * S_LEN + qt * 32 + q) * S_LEN + h5 * 4;

  float m_ = -1e30f, l_ = 0.f;   // ln-domain running max / sum
  floatx16 acco[4] = {};         // O^T: col=q (lane-local), row = d

  // prologue: stage kt=0
  stage_k128(qkv, b, 0, lK[0], wid, lane);
  stage_v128(vt, b, 0, lV[0], wid, lane);
  __syncthreads();

  int buf = 0;
  for (int kt = 0; kt < NT2; ++kt) {
    if (kt + 1 < NT2) {
      stage_k128(qkv, b, kt + 1, lK[buf ^ 1], wid, lane);
      stage_v128(vt, b, kt + 1, lV[buf ^ 1], wid, lane);
    }
    const char* pKb = (const char*)&lK[buf][0];
    const char* pVb = (const char*)&lV[buf][0];

#pragma unroll
    for (int half = 0; half < 2; ++half) {
      // mask loads for this 64-key half (global, L2/L3-resident)
      const float* mh = mptr + kt * 128 + half * 64;
      floatx4 mk[8];
#pragma unroll
      for (int kb = 0; kb < 2; ++kb)
#pragma unroll
        for (int rg = 0; rg < 4; ++rg)
          mk[kb * 4 + rg] = *(const floatx4*)(mh + kb * 32 + rg * 8);

      // ---- QK^T swapped: accs = K * Q^T = S^T (col = q = lane&31) ----
      floatx16 accs0 = {}, accs1 = {};
      const char* pK = pKb + half * 16384;
      __builtin_amdgcn_s_setprio(1);
#pragma unroll
      for (int cs = 0; cs < 8; ++cs) {
        bf16x8 kf0 = *(const bf16x8*)(pK + offK[cs]);
        bf16x8 kf1 = *(const bf16x8*)(pK + 8192 + offK[cs]);
        accs0 = mfma32(kf0, qf[cs], accs0, 0, 0, 0);
        accs1 = mfma32(kf1, qf[cs], accs1, 0, 0, 0);
      }
      __builtin_amdgcn_s_setprio(0);

      // ---- online softmax (ln-domain scores; exp2 via fused LOG2E fma) ----
      float pr[32];
      float pm0 = -1e30f, pm1 = -1e30f, pm2 = -1e30f, pm3 = -1e30f;
#pragma unroll
      for (int kb = 0; kb < 2; ++kb)
#pragma unroll
        for (int rg = 0; rg < 4; ++rg) {
          floatx4 m4 = mk[kb * 4 + rg];
          float s0 = (kb ? accs1[rg * 4 + 0] : accs0[rg * 4 + 0]) * scale + m4[0];
          float s1 = (kb ? accs1[rg * 4 + 1] : accs0[rg * 4 + 1]) * scale + m4[1];
          float s2 = (kb ? accs1[rg * 4 + 2] : accs0[rg * 4 + 2]) * scale + m4[2];
          float s3 = (kb ? accs1[rg * 4 + 3] : accs0[rg * 4 + 3]) * scale + m4[3];
          pr[kb * 16 + rg * 4 + 0] = s0; pm0 = fmaxf(pm0, s0);
          pr[kb * 16 + rg * 4 + 1] = s1; pm1 = fmaxf(pm1, s1);
          pr[kb * 16 + rg * 4 + 2] = s2; pm2 = fmaxf(pm2, s2);
          pr[kb * 16 + rg * 4 + 3] = s3; pm3 = fmaxf(pm3, s3);
        }
      float rowm = red_max32(fmaxf(fmaxf(pm0, pm1), fmaxf(pm2, pm3)));

      // defer-max (T13): only rescale when max grows by > 8 (ln units)
      if (__any(rowm > m_ + 8.0f)) {
        float mn = fmaxf(m_, rowm);
        float al = fexp2((m_ - mn) * LOG2E);
        m_ = mn;
        l_ *= al;
#pragma unroll
        for (int dt = 0; dt < 4; ++dt) acco[dt] *= al;
      }
      float nml2 = -m_ * LOG2E;
      float ps0 = 0.f, ps1 = 0.f, ps2 = 0.f, ps3 = 0.f;
#pragma unroll
      for (int j = 0; j < 32; j += 4) {
        float e0 = fexp2(pr[j + 0] * LOG2E + nml2); pr[j + 0] = e0; ps0 += e0;
        float e1 = fexp2(pr[j + 1] * LOG2E + nml2); pr[j + 1] = e1; ps1 += e1;
        float e2 = fexp2(pr[j + 2] * LOG2E + nml2); pr[j + 2] = e2; ps2 += e2;
        float e3 = fexp2(pr[j + 3] * LOG2E + nml2); pr[j + 3] = e3; ps3 += e3;
      }
      l_ += red_add32((ps0 + ps1) + (ps2 + ps3));

      // ---- pack P into PV B-fragments (cvt_pk + permlane32_swap) ----
      bf16x8 pf[4];
#pragma unroll
      for (int kb = 0; kb < 2; ++kb)
#pragma unroll
        for (int s = 0; s < 2; ++s) {
          int base = kb * 16 + s * 8;
          int A0 = cvtpk(pr[base + 0], pr[base + 1]);
          int A1 = cvtpk(pr[base + 2], pr[base + 3]);
          int B0 = cvtpk(pr[base + 4], pr[base + 5]);
          int B1 = cvtpk(pr[base + 6], pr[base + 7]);
          half_swap(A0, B0);
          half_swap(A1, B1);
          intx4 w;
          w[0] = A0; w[1] = A1; w[2] = B0; w[3] = B1;
          pf[kb * 2 + s] = __builtin_bit_cast(bf16x8, w);
        }

      // ---- PV swapped: acco += V^T * P^T = O^T (col = q) ----
      __builtin_amdgcn_s_setprio(1);
#pragma unroll
      for (int dt = 0; dt < 4; ++dt)
#pragma unroll
        for (int ks = 0; ks < 4; ++ks) {
          bf16x8 vf = *(const bf16x8*)(pVb + dt * 8192 + offV[half * 4 + ks]);
          acco[dt] = mfma32(vf, pf[ks], acco[dt], 0, 0, 0);
        }
      __builtin_amdgcn_s_setprio(0);
    }

    __syncthreads();
    buf ^= 1;
  }

  // ---- epilogue: attn[q][h*HD + d] = O/l ----
  float inv = 1.0f / l_;
  u16* obase = attn + qrow * DIMSZ + h * HD;
#pragma unroll
  for (int dt = 0; dt < 4; ++dt)
#pragma unroll
    for (int rg = 0; rg < 4; ++rg) {
      int d0 = dt * 32 + rg * 8 + h5 * 4;
      ushort4 st;
      st.x = f2bf(acco[dt][rg * 4 + 0] * inv);
      st.y = f2bf(acco[dt][rg * 4 + 1] * inv);
      st.z = f2bf(acco[dt][rg * 4 + 2] * inv);
      st.w = f2bf(acco[dt][rg * 4 + 3] * inv);
      *(ushort4*)(obase + d0) = st;
    }
}

// ---------------- launch ----------------
extern "C" void kernel_launch(void* const* d_in, const int* in_sizes, int n_in,
                              void* d_out, int out_size, void* d_ws, size_t ws_size,
                              hipStream_t stream) {
  const float* hidden = (const float*)d_in[0];
  const float* mask   = (const float*)d_in[1];
  const float* wq = (const float*)d_in[2];
  const float* bq = (const float*)d_in[3];
  const float* wk = (const float*)d_in[4];
  const float* bk = (const float*)d_in[5];
  const float* wv = (const float*)d_in[6];
  const float* bv = (const float*)d_in[7];
  const float* wo = (const float*)d_in[8];
  const float* bo = (const float*)d_in[9];
  float* out = (float*)d_out;

  // workspace layout (total ~71.3 MB)
  char* ws = (char*)d_ws;
  u16*   hb    = (u16*)(ws);                    // hidden bf16: 4096x2048
  u16*   wqkvT = (u16*)(ws + 16777216);         // [wq^T; wk^T; wv^T]: 2304x2048
  u16*   woT   = (u16*)(ws + 26214400);         // wo^T: 2048x2048
  float* bqkv  = (float*)(ws + 34603008);       // 2304 f32
  u16*   qkv   = (u16*)(ws + 34612224);         // 4096x2304
  u16*   vt    = (u16*)(ws + 53486592);         // 2 x 128 x 2048
  u16*   attn  = (u16*)(ws + 54535168);         // 4096x2048

  k_cvt_bf16<<<dim3(8192), dim3(256), 0, stream>>>(hidden, hb, 4096 * 2048 / 4);
  k_transpose_bf16<<<dim3(32, 32), dim3(256), 0, stream>>>(wq, wqkvT, 2048, 2048, 0);
  k_transpose_bf16<<<dim3(2, 32),  dim3(256), 0, stream>>>(wk, wqkvT, 2048, 128, 2048);
  k_transpose_bf16<<<dim3(2, 32),  dim3(256), 0, stream>>>(wv, wqkvT, 2048, 128, NQK);
  k_transpose_bf16<<<dim3(32, 32), dim3(256), 0, stream>>>(wo, woT, 2048, 2048, 0);
  k_bias_concat<<<dim3(9), dim3(256), 0, stream>>>(bq, bk, bv, bqkv);

  k_gemm<0><<<dim3(32, 18), dim3(256), 0, stream>>>(hb, wqkvT, bqkv, (void*)qkv, vt, 4096, NQKV, 2048);
  k_attn<<<dim3(64, 2, 2), dim3(512), 0, stream>>>(qkv, vt, mask, attn);
  k_gemm<1><<<dim3(32, 16), dim3(256), 0, stream>>>(attn, woT, bo, (void*)out, (u16*)nullptr, 4096, 2048, 2048);
}

// Round 8
// 204.163 us; speedup vs baseline: 1.0594x; 1.0594x over previous
//
#include <hip/hip_runtime.h>
#include <hip/hip_bf16.h>
#include <stdint.h>

#define S_LEN 2048
#define DIMSZ 2048
#define NH    16
#define HD    128
#define NQK   2176   // Q cols (2048) + K cols (128); V cols start here
#define NQKV  2304
#define NT    (S_LEN / 64)

typedef short  bf16x8  __attribute__((ext_vector_type(8)));
typedef float  floatx4 __attribute__((ext_vector_type(4)));
typedef float  floatx16 __attribute__((ext_vector_type(16)));
typedef int    intx4   __attribute__((ext_vector_type(4)));
typedef unsigned short u16;

#define mfma32 __builtin_amdgcn_mfma_f32_32x32x16_bf16
#define LOG2E 1.4426950408889634f

// round-to-nearest-even f32 -> bf16 bits
__device__ __forceinline__ u16 f2bf(float x) {
  unsigned int u = __builtin_bit_cast(unsigned int, x);
  u = (u + 0x7FFFu + ((u >> 16) & 1u)) >> 16;
  return (u16)u;
}

// v_cvt_pk_bf16_f32: word = (bf16(hi)<<16) | bf16(lo)   (plain VALU, no hazard)
__device__ __forceinline__ int cvtpk(float lo, float hi) {
  int r;
  asm("v_cvt_pk_bf16_f32 %0, %1, %2" : "=v"(r) : "v"(lo), "v"(hi));
  return r;
}

// 2^x — builtin so the compiler handles the TRANS wait-state hazard
#if __has_builtin(__builtin_amdgcn_exp2f)
__device__ __forceinline__ float fexp2(float x) { return __builtin_amdgcn_exp2f(x); }
#else
__device__ __forceinline__ float fexp2(float x) { return exp2f(x); }
#endif

// half swap via BUILTIN (hazard-modeled): a'[32:63]=b[0:31], b'[0:31]=a[32:63]
#if __has_builtin(__builtin_amdgcn_permlane32_swap)
__device__ __forceinline__ void half_swap(int& a, int& b) {
  auto r = __builtin_amdgcn_permlane32_swap(a, b, false, false);
  a = (int)r[0]; b = (int)r[1];
}
__device__ __forceinline__ float red_max32(float x) {
  int xi = __builtin_bit_cast(int, x);
  auto r = __builtin_amdgcn_permlane32_swap(xi, xi, false, false);
  return fmaxf(__builtin_bit_cast(float, (int)r[0]), __builtin_bit_cast(float, (int)r[1]));
}
__device__ __forceinline__ float red_add32(float x) {
  int xi = __builtin_bit_cast(int, x);
  auto r = __builtin_amdgcn_permlane32_swap(xi, xi, false, false);
  return __builtin_bit_cast(float, (int)r[0]) + __builtin_bit_cast(float, (int)r[1]);
}
#else
__device__ __forceinline__ void half_swap(int& a, int& b) {
  int as = __shfl_xor(a, 32);
  int bs = __shfl_xor(b, 32);
  int lane = threadIdx.x & 63;
  int na = (lane < 32) ? a : bs;
  int nb = (lane < 32) ? as : b;
  a = na; b = nb;
}
__device__ __forceinline__ float red_max32(float x) { return fmaxf(x, __shfl_xor(x, 32)); }
__device__ __forceinline__ float red_add32(float x) { return x + __shfl_xor(x, 32); }
#endif

// async global->LDS, 16 bytes per lane; LDS dest wave-uniform base (+lane*16 by HW)
__device__ __forceinline__ void gload16(const void* g, void* l) {
  __builtin_amdgcn_global_load_lds(
      reinterpret_cast<const __attribute__((address_space(1))) void*>(reinterpret_cast<uintptr_t>(g)),
      reinterpret_cast<__attribute__((address_space(3))) void*>(reinterpret_cast<uintptr_t>(l)),
      16, 0, 0);
}

// ---------------- converts ----------------
__global__ void k_cvt_bf16(const float* __restrict__ in, u16* __restrict__ out, int n4) {
  int i = blockIdx.x * blockDim.x + threadIdx.x;
  if (i < n4) {
    float4 v = ((const float4*)in)[i];
    ushort4 o;
    o.x = f2bf(v.x); o.y = f2bf(v.y); o.z = f2bf(v.z); o.w = f2bf(v.w);
    ((ushort4*)out)[i] = o;
  }
}

// in: (K x N) f32 row-major  ->  out rows [rowOff .. rowOff+N): (N x K) bf16
__global__ void k_transpose_bf16(const float* __restrict__ in, u16* __restrict__ out,
                                 int K, int N, int rowOff) {
  __shared__ float t[64][65];
  int c0 = blockIdx.x * 64;   // N dim
  int r0 = blockIdx.y * 64;   // K dim
  int tid = threadIdx.x;
  int lr = tid >> 6;          // 0..3
  int lc = tid & 63;
#pragma unroll
  for (int i = 0; i < 16; ++i) {
    int r = lr + i * 4;
    t[r][lc] = in[(size_t)(r0 + r) * N + c0 + lc];
  }
  __syncthreads();
#pragma unroll
  for (int i = 0; i < 16; ++i) {
    int r = lr + i * 4;  // row of transposed tile (= col of in)
    out[(size_t)(rowOff + c0 + r) * K + r0 + lc] = f2bf(t[lc][r]);
  }
}

__global__ void k_bias_concat(const float* __restrict__ bq, const float* __restrict__ bk,
                              const float* __restrict__ bv, float* __restrict__ out) {
  int i = blockIdx.x * 256 + threadIdx.x;
  if (i < NQKV) out[i] = (i < 2048) ? bq[i] : (i < NQK ? bk[i - 2048] : bv[i - NQK]);
}

// ---------------- GEMM: C(MxN) = A(MxK) * Bt(NxK)^T + bias ----------------
// 128x128 block tile, 4 waves (2M x 2N), BK=32, double-buffered, LDS 32KB total
// -> up to ~4 co-resident blocks/CU (the experiment of this round).
// LDS tile layout: 128 rows x 32 cols bf16 = 64B rows = 4 chunks of 16B.
// Swizzle: slot = chunk ^ ((row>>1)&3)  -> reads are 2-way bank-aliased (free, m136).
__device__ __forceinline__ void stage_tile32(const u16* __restrict__ G, int ldg, int row0, int kt,
                                             u16* lbase, int wid, int lane) {
#pragma unroll
  for (int i = 0; i < 2; ++i) {
    int c   = (wid * 2 + i) * 64 + lane;   // 0..511 chunk id
    int row = c >> 2, cin = c & 3;
    int cs  = cin ^ ((row >> 1) & 3);      // source pre-swizzle (rule #21)
    const u16* g = G + (size_t)(row0 + row) * ldg + kt * 32 + cs * 8;
    gload16(g, (char*)lbase + (wid * 2 + i) * 1024);
  }
}

template <int OMODE>
__global__ __launch_bounds__(256, 3)
void k_gemm(const u16* __restrict__ A, const u16* __restrict__ Bt,
            const float* __restrict__ bias, void* __restrict__ Cout,
            u16* __restrict__ vt, int M, int N, int K) {
  __shared__ u16 lA[2][128 * 32];
  __shared__ u16 lB[2][128 * 32];
  const int tid = threadIdx.x, lane = tid & 63, wid = tid >> 6;
  const int wm = wid >> 1, wn = wid & 1;
  const int tm = blockIdx.x, tn = blockIdx.y;
  const int nk = K >> 5;
  const int g3 = lane >> 4;   // k-group 0..3 = chunk index

  stage_tile32(A, K, tm * 128, 0, lA[0], wid, lane);
  stage_tile32(Bt, K, tn * 128, 0, lB[0], wid, lane);
  __syncthreads();

  floatx4 acc[4][4] = {};
  int buf = 0;
  for (int kt = 0; kt < nk; ++kt) {
    if (kt + 1 < nk) {
      stage_tile32(A, K, tm * 128, kt + 1, lA[buf ^ 1], wid, lane);
      stage_tile32(Bt, K, tn * 128, kt + 1, lB[buf ^ 1], wid, lane);
    }
    const char* pa = (const char*)&lA[buf][0];
    const char* pb = (const char*)&lB[buf][0];
    bf16x8 af[4], bfr[4];
#pragma unroll
    for (int f = 0; f < 4; ++f) {
      int ra = wm * 64 + f * 16 + (lane & 15);
      af[f]  = *(const bf16x8*)(pa + ra * 64 + ((g3 ^ ((ra >> 1) & 3)) << 4));
      int rb = wn * 64 + f * 16 + (lane & 15);
      bfr[f] = *(const bf16x8*)(pb + rb * 64 + ((g3 ^ ((rb >> 1) & 3)) << 4));
    }
    __builtin_amdgcn_s_setprio(1);
#pragma unroll
    for (int fm = 0; fm < 4; ++fm)
#pragma unroll
      for (int fn = 0; fn < 4; ++fn)
        acc[fm][fn] = __builtin_amdgcn_mfma_f32_16x16x32_bf16(af[fm], bfr[fn], acc[fm][fn], 0, 0, 0);
    __builtin_amdgcn_s_setprio(0);
    __syncthreads();
    buf ^= 1;
  }

#pragma unroll
  for (int fm = 0; fm < 4; ++fm)
#pragma unroll
    for (int fn = 0; fn < 4; ++fn)
#pragma unroll
      for (int r = 0; r < 4; ++r) {
        int rowg = tm * 128 + wm * 64 + fm * 16 + (lane >> 4) * 4 + r;
        int colg = tn * 128 + wn * 64 + fn * 16 + (lane & 15);
        float v = acc[fm][fn][r] + bias[colg];
        if constexpr (OMODE == 1) {
          ((float*)Cout)[(size_t)rowg * N + colg] = v;
        } else {
          if (colg < NQK) {
            ((u16*)Cout)[(size_t)rowg * N + colg] = f2bf(v);
          } else {  // V: store transposed vt[b][d][s]
            int d = colg - NQK;
            int bg = rowg >> 11, s = rowg & 2047;
            vt[((size_t)bg * HD + d) * S_LEN + s] = f2bf(v);
          }
        }
      }
}

// ---------------- flash attention (R4-proven: 8-wave, swapped-operand, lM-staged) ----
// grid (S/32, 2, B); 512 threads = 8 waves; wave w = head hg*8+w, all on same 32 q-rows.
__device__ __forceinline__ void stage_kv(const u16* __restrict__ qkv, const u16* __restrict__ vt,
                                         int b, int kt, u16* lK, u16* lV, int wid, int lane) {
#pragma unroll
  for (int i = 0; i < 2; ++i) {
    int seg = wid * 2 + i;
    {  // K tile: 64 rows x 256B (16 chunks), slot cin holds logical cin^(r&7)
      int r = seg * 4 + (lane >> 4), cin = lane & 15;
      const u16* g = qkv + (size_t)(b * S_LEN + kt * 64 + r) * NQKV + 2048 + ((cin ^ (r & 7)) * 8);
      gload16(g, (char*)lK + seg * 1024);
    }
    {  // Vt tile: 128 rows x 128B (8 chunks)
      int r = seg * 8 + (lane >> 3), cin = lane & 7;
      const u16* g = vt + ((size_t)b * HD + r) * S_LEN + kt * 64 + ((cin ^ (r & 7)) * 8);
      gload16(g, (char*)lV + seg * 1024);
    }
  }
}

__global__ __launch_bounds__(512)
void k_attn(const u16* __restrict__ qkv, const u16* __restrict__ vt,
            const float* __restrict__ mask, u16* __restrict__ attn) {
  __shared__ __align__(16) u16   lK[2][64 * 128];
  __shared__ __align__(16) u16   lV[2][128 * 64];
  __shared__ __align__(16) float lM[2][32 * 64];   // mask pre-scaled by log2e
  const int tid = threadIdx.x, lane = tid & 63, wid = tid >> 6;
  const int qt = blockIdx.x, hg = blockIdx.y, b = blockIdx.z;
  const int h = hg * 8 + wid;
  const int q = lane & 31, h5 = lane >> 5;
  const float c_sl2 = 0.08838834764831845f * LOG2E;  // scale * log2(e)

  // hoist Q (B-frag: col=q, d = cs*16 + h5*8 + idx)
  bf16x8 qf[8];
  const size_t qrow = (size_t)(b * S_LEN + qt * 32 + q);
#pragma unroll
  for (int cs = 0; cs < 8; ++cs)
    qf[cs] = *(const bf16x8*)(qkv + qrow * NQKV + h * HD + cs * 16 + h5 * 8);

  float m_ = -1e30f, l_ = 0.f;   // log2-domain running max / sum
  floatx16 acco[4] = {};         // O^T: col=q (lane-local), row = d

  // mask stage helpers
  const int mq = tid >> 4, mc = tid & 15;
  const float* mrow = mask + (size_t)b * S_LEN * S_LEN + (size_t)(qt * 32 + mq) * S_LEN + mc * 4;

  // prologue: stage kt=0
  stage_kv(qkv, vt, b, 0, lK[0], lV[0], wid, lane);
  floatx4 mreg = *(const floatx4*)(mrow);
  *(floatx4*)((char*)&lM[0][0] + mq * 256 + ((mc ^ (mq & 7)) << 4)) = mreg * LOG2E;
  __syncthreads();

  int buf = 0;
  for (int kt = 0; kt < NT; ++kt) {
    if (kt + 1 < NT) {
      stage_kv(qkv, vt, b, kt + 1, lK[buf ^ 1], lV[buf ^ 1], wid, lane);
      mreg = *(const floatx4*)(mrow + (size_t)(kt + 1) * 64);
    }

    // ---- QK^T swapped: accs = K * Q^T = S^T (col = q = lane&31) ----
    floatx16 accs0 = {}, accs1 = {};
    const char* pK = (const char*)&lK[buf][0];
    __builtin_amdgcn_s_setprio(1);
#pragma unroll
    for (int cs = 0; cs < 8; ++cs) {
      int c = cs * 2 + h5;
      bf16x8 kf0 = *(const bf16x8*)(pK + q * 256 + ((c ^ (q & 7)) << 4));
      bf16x8 kf1 = *(const bf16x8*)(pK + (32 + q) * 256 + ((c ^ (q & 7)) << 4));
      accs0 = mfma32(kf0, qf[cs], accs0, 0, 0, 0);
      accs1 = mfma32(kf1, qf[cs], accs1, 0, 0, 0);
    }
    __builtin_amdgcn_s_setprio(0);

    // ---- online softmax, log2 domain, fully in-register ----
    float pr[32];
    float pm0 = -1e30f, pm1 = -1e30f, pm2 = -1e30f, pm3 = -1e30f;
    const char* pM = (const char*)&lM[buf][0];
#pragma unroll
    for (int kb = 0; kb < 2; ++kb)
#pragma unroll
      for (int rg = 0; rg < 4; ++rg) {
        int c = kb * 8 + rg * 2 + h5;
        floatx4 m4 = *(const floatx4*)(pM + q * 256 + ((c ^ (q & 7)) << 4));
        float s0 = (kb ? accs1[rg * 4 + 0] : accs0[rg * 4 + 0]) * c_sl2 + m4[0];
        float s1 = (kb ? accs1[rg * 4 + 1] : accs0[rg * 4 + 1]) * c_sl2 + m4[1];
        float s2 = (kb ? accs1[rg * 4 + 2] : accs0[rg * 4 + 2]) * c_sl2 + m4[2];
        float s3 = (kb ? accs1[rg * 4 + 3] : accs0[rg * 4 + 3]) * c_sl2 + m4[3];
        pr[kb * 16 + rg * 4 + 0] = s0; pm0 = fmaxf(pm0, s0);
        pr[kb * 16 + rg * 4 + 1] = s1; pm1 = fmaxf(pm1, s1);
        pr[kb * 16 + rg * 4 + 2] = s2; pm2 = fmaxf(pm2, s2);
        pr[kb * 16 + rg * 4 + 3] = s3; pm3 = fmaxf(pm3, s3);
      }
    float rowm = red_max32(fmaxf(fmaxf(pm0, pm1), fmaxf(pm2, pm3)));

    // defer-max (T13): only rescale when max grows by > 8/ln2 (log2 units)
    if (__any(rowm > m_ + 11.5415603f)) {
      float mn = fmaxf(m_, rowm);
      float al = fexp2(m_ - mn);
      m_ = mn;
      l_ *= al;
#pragma unroll
      for (int dt = 0; dt < 4; ++dt) acco[dt] *= al;
    }
    float ps0 = 0.f, ps1 = 0.f, ps2 = 0.f, ps3 = 0.f;
#pragma unroll
    for (int j = 0; j < 32; j += 4) {
      float e0 = fexp2(pr[j + 0] - m_); pr[j + 0] = e0; ps0 += e0;
      float e1 = fexp2(pr[j + 1] - m_); pr[j + 1] = e1; ps1 += e1;
      float e2 = fexp2(pr[j + 2] - m_); pr[j + 2] = e2; ps2 += e2;
      float e3 = fexp2(pr[j + 3] - m_); pr[j + 3] = e3; ps3 += e3;
    }
    l_ += red_add32((ps0 + ps1) + (ps2 + ps3));

    // ---- pack P into PV B-fragments (cvt_pk + permlane32_swap, no LDS/DS) ----
    bf16x8 pf[4];
#pragma unroll
    for (int kb = 0; kb < 2; ++kb)
#pragma unroll
      for (int s = 0; s < 2; ++s) {
        int base = kb * 16 + s * 8;
        int A0 = cvtpk(pr[base + 0], pr[base + 1]);
        int A1 = cvtpk(pr[base + 2], pr[base + 3]);
        int B0 = cvtpk(pr[base + 4], pr[base + 5]);
        int B1 = cvtpk(pr[base + 6], pr[base + 7]);
        half_swap(A0, B0);
        half_swap(A1, B1);
        intx4 w;
        w[0] = A0; w[1] = A1; w[2] = B0; w[3] = B1;
        pf[kb * 2 + s] = __builtin_bit_cast(bf16x8, w);
      }

    // ---- PV swapped: acco += Vt * P^T = O^T (col = q) ----
    const char* pV = (const char*)&lV[buf][0];
    __builtin_amdgcn_s_setprio(1);
#pragma unroll
    for (int dt = 0; dt < 4; ++dt) {
      int rd = dt * 32 + q;
#pragma unroll
      for (int ks = 0; ks < 4; ++ks) {
        int c = ks * 2 + h5;
        bf16x8 vf = *(const bf16x8*)(pV + rd * 128 + ((c ^ (q & 7)) << 4));
        acco[dt] = mfma32(vf, pf[ks], acco[dt], 0, 0, 0);
      }
    }
    __builtin_amdgcn_s_setprio(0);

    if (kt + 1 < NT)
      *(floatx4*)((char*)&lM[buf ^ 1][0] + mq * 256 + ((mc ^ (mq & 7)) << 4)) = mreg * LOG2E;
    __syncthreads();
    buf ^= 1;
  }

  // ---- epilogue: attn[q][h*HD + d] = O/l ----
  float inv = 1.0f / l_;
  u16* obase = attn + qrow * DIMSZ + h * HD;
#pragma unroll
  for (int dt = 0; dt < 4; ++dt)
#pragma unroll
    for (int rg = 0; rg < 4; ++rg) {
      int d0 = dt * 32 + rg * 8 + h5 * 4;
      ushort4 st;
      st.x = f2bf(acco[dt][rg * 4 + 0] * inv);
      st.y = f2bf(acco[dt][rg * 4 + 1] * inv);
      st.z = f2bf(acco[dt][rg * 4 + 2] * inv);
      st.w = f2bf(acco[dt][rg * 4 + 3] * inv);
      *(ushort4*)(obase + d0) = st;
    }
}

// ---------------- launch ----------------
extern "C" void kernel_launch(void* const* d_in, const int* in_sizes, int n_in,
                              void* d_out, int out_size, void* d_ws, size_t ws_size,
                              hipStream_t stream) {
  const float* hidden = (const float*)d_in[0];
  const float* mask   = (const float*)d_in[1];
  const float* wq = (const float*)d_in[2];
  const float* bq = (const float*)d_in[3];
  const float* wk = (const float*)d_in[4];
  const float* bk = (const float*)d_in[5];
  const float* wv = (const float*)d_in[6];
  const float* bv = (const float*)d_in[7];
  const float* wo = (const float*)d_in[8];
  const float* bo = (const float*)d_in[9];
  float* out = (float*)d_out;

  // workspace layout (total ~71.3 MB)
  char* ws = (char*)d_ws;
  u16*   hb    = (u16*)(ws);                    // hidden bf16: 4096x2048
  u16*   wqkvT = (u16*)(ws + 16777216);         // [wq^T; wk^T; wv^T]: 2304x2048
  u16*   woT   = (u16*)(ws + 26214400);         // wo^T: 2048x2048
  float* bqkv  = (float*)(ws + 34603008);       // 2304 f32
  u16*   qkv   = (u16*)(ws + 34612224);         // 4096x2304
  u16*   vt    = (u16*)(ws + 53486592);         // 2 x 128 x 2048
  u16*   attn  = (u16*)(ws + 54535168);         // 4096x2048

  k_cvt_bf16<<<dim3(8192), dim3(256), 0, stream>>>(hidden, hb, 4096 * 2048 / 4);
  k_transpose_bf16<<<dim3(32, 32), dim3(256), 0, stream>>>(wq, wqkvT, 2048, 2048, 0);
  k_transpose_bf16<<<dim3(2, 32),  dim3(256), 0, stream>>>(wk, wqkvT, 2048, 128, 2048);
  k_transpose_bf16<<<dim3(2, 32),  dim3(256), 0, stream>>>(wv, wqkvT, 2048, 128, NQK);
  k_transpose_bf16<<<dim3(32, 32), dim3(256), 0, stream>>>(wo, woT, 2048, 2048, 0);
  k_bias_concat<<<dim3(9), dim3(256), 0, stream>>>(bq, bk, bv, bqkv);

  k_gemm<0><<<dim3(32, 18), dim3(256), 0, stream>>>(hb, wqkvT, bqkv, (void*)qkv, vt, 4096, NQKV, 2048);
  k_attn<<<dim3(64, 2, 2), dim3(512), 0, stream>>>(qkv, vt, mask, attn);
  k_gemm<1><<<dim3(32, 16), dim3(256), 0, stream>>>(attn, woT, bo, (void*)out, (u16*)nullptr, 4096, 2048, 2048);
}